// Round 2
// baseline (505.739 us; speedup 1.0000x reference)
//
#include <hip/hip_runtime.h>
#include <cmath>

// Problem constants (from reference)
#define C_DIM 8000
#define N_TOTAL 10500
#define B_DIM 256
#define N_ROWS (B_DIM * 4)

// Online-softmax single-element step. Strict '>' keeps the earliest index
// within a thread's ascending-index stream (matches jnp.argmax tie-break).
__device__ __forceinline__ void step(float& m, float& s, int& idx, float v, int c) {
    if (v > m) {
        s = s * __expf(m - v) + 1.0f;   // __expf(-inf) = 0 handles first element
        m = v;
        idx = c;
    } else {
        s += __expf(v - m);             // v == m -> +1.0, idx keeps earlier index
    }
}

// Merge two online-softmax/argmax states (first-index tie-break).
__device__ __forceinline__ void merge_sa(float& m, float& s, int& idx,
                                         float m2, float s2, int i2) {
    if (m2 > m) {
        s = s * __expf(m - m2) + s2;
        m = m2;
        idx = i2;
    } else if (m2 == m) {               // covers both-(-inf) and exact ties
        s += s2;
        if (i2 < idx) idx = i2;
    } else {
        s += s2 * __expf(m2 - m);
    }
}

// One block per row (row = b*4 + j); the last block to finish also does the
// final per-sample combine + block reduction (saves a second kernel launch).
__global__ __launch_bounds__(256) void fused_kernel(const float* __restrict__ yp,
                                                    const int* __restrict__ yt,
                                                    const float* __restrict__ H,
                                                    int* __restrict__ counter,
                                                    float* __restrict__ ws_nll,
                                                    int* __restrict__ ws_arg,
                                                    float* __restrict__ out) {
    const int row = blockIdx.x;         // b*4 + j
    const int j = row & 3;
    const int tid = threadIdx.x;
    const int SIZES[4] = {100, 400, 2000, 8000};
    const int OFFS[4]  = {0, 100, 500, 2500};
    const int n = SIZES[j];
    const float* rowp = yp + (size_t)row * C_DIM;

    // ---- online softmax + argmax over the valid prefix, float4 loads ----
    float m = -INFINITY, s = 0.0f;
    int idx = 0x7fffffff;
    const float4* rowp4 = (const float4*)rowp;  // row base is 16B-aligned
    const int n4 = n >> 2;                      // all sizes divisible by 4
    for (int c4 = tid; c4 < n4; c4 += 256) {
        float4 v = rowp4[c4];
        const int base = c4 << 2;
        step(m, s, idx, v.x, base + 0);
        step(m, s, idx, v.y, base + 1);
        step(m, s, idx, v.z, base + 2);
        step(m, s, idx, v.w, base + 3);
    }

    // wave (64-lane) reduce
    for (int off = 32; off; off >>= 1) {
        float m2 = __shfl_down(m, off, 64);
        float s2 = __shfl_down(s, off, 64);
        int   i2 = __shfl_down(idx, off, 64);
        merge_sa(m, s, idx, m2, s2, i2);
    }

    // cross-wave merge via LDS (4 waves)
    __shared__ float sm[4], ss[4];
    __shared__ int si[4];
    __shared__ float red[4];
    __shared__ int isLast;
    const int wave = tid >> 6;
    if ((tid & 63) == 0) { sm[wave] = m; ss[wave] = s; si[wave] = idx; }
    __syncthreads();
    if (tid == 0) {
        m = sm[0]; s = ss[0]; idx = si[0];
        for (int w = 1; w < 4; ++w) merge_sa(m, s, idx, sm[w], ss[w], si[w]);
        const int t = yt[row];
        ws_nll[row] = -(rowp[t] - (m + logf(s)));   // NLL at target
        ws_arg[row] = idx + OFFS[j];                // global hierarchy index
        __threadfence();                            // publish ws before counter
        int prev = atomicAdd(counter, 1);
        isLast = (prev == N_ROWS - 1) ? 1 : 0;
    }
    __syncthreads();
    if (!isLast) return;

    // ---- last block: per-sample combine + deterministic block reduce ----
    __threadfence();                    // acquire: see all blocks' ws writes
    const int b = tid;                  // one thread per sample
    const float W1 = 0.25f, W2 = 0.15f, W3 = 0.10f;
    const float E = 2.718281828459045f; // float32 np.e

    const int g0 = ws_arg[b * 4 + 0];
    const int g1 = ws_arg[b * 4 + 1];
    const int g2 = ws_arg[b * 4 + 2];
    const int g3 = ws_arg[b * 4 + 3];

    float p = 0.0f;
    p += W1 * (ws_nll[b * 4 + 1] * (1.0f / 256.0f));
    p += W2 * (ws_nll[b * 4 + 2] * (1.0f / 256.0f));
    p += W3 * (ws_nll[b * 4 + 3] * (1.0f / 256.0f));
    p += W1 * E * ((H[(size_t)g0 * N_TOTAL + g1] == 1.0f) ? 1.0f : 0.0f);
    p += W2 * E * ((H[(size_t)g1 * N_TOTAL + g2] == 1.0f) ? 1.0f : 0.0f);
    p += W3 * E * ((H[(size_t)g2 * N_TOTAL + g3] == 1.0f) ? 1.0f : 0.0f);

    for (int off = 32; off; off >>= 1) p += __shfl_down(p, off, 64);
    if ((tid & 63) == 0) red[tid >> 6] = p;
    __syncthreads();
    if (tid == 0) out[0] = red[0] + red[1] + red[2] + red[3];
}

extern "C" void kernel_launch(void* const* d_in, const int* in_sizes, int n_in,
                              void* d_out, int out_size, void* d_ws, size_t ws_size,
                              hipStream_t stream) {
    const float* yp = (const float*)d_in[0];   // y_pred (256, 4, 8000) f32
    const int*   yt = (const int*)d_in[1];     // y_true (256, 4) i32
    const float* H  = (const float*)d_in[2];   // H (10500, 10500) f32

    // ws layout: [0..3] completion counter, [64..] nll floats, then arg ints
    int*   counter = (int*)d_ws;
    float* ws_nll  = (float*)((char*)d_ws + 64);
    int*   ws_arg  = (int*)((char*)d_ws + 64 + N_ROWS * sizeof(float));

    hipMemsetAsync(counter, 0, sizeof(int), stream);   // ws is 0xAA-poisoned
    fused_kernel<<<N_ROWS, 256, 0, stream>>>(yp, yt, H, counter,
                                             ws_nll, ws_arg, (float*)d_out);
}